// Round 1
// baseline (307.691 us; speedup 1.0000x reference)
//
#include <hip/hip_runtime.h>

// Multires hash-grid encode (2D, instant-NGP style), exact replication of the
// jax reference's index math:
//   fx = x * scale (fp32); int_x[c] = trunc_i64(fx + c) with fp32 add;
//   frac = fx - (float)trunc_i64(fx);
//   levels 0..5 dense grid: idx = ix*(scale+1)+iy
//   levels 6..15 hashed:    idx = (ix ^ (iy*19349663)) % 524309
//   bilinear weights clip(1-frac)/clip(frac) per axis, product over xy.
// One thread per point; 16 levels fully unrolled; output 32 floats/point
// written as 8x float4.

static constexpr int  kPoints    = 524288;
static constexpr int  kLevels    = 16;
static constexpr int  kStartHash = 6;
static constexpr long long kPs1     = 19349663LL;
static constexpr long long kEntries = 524309LL;

__global__ __launch_bounds__(256) void hashgrid_fwd(
    const float2* __restrict__ x,
    const float2* __restrict__ tbl,
    float4* __restrict__ out)
{
    const int n = blockIdx.x * blockDim.x + threadIdx.x;
    if (n >= kPoints) return;

    const float2 p = x[n];

    // Per-level base offsets into the flat table (precomputed from the
    // reference: sizes (res+1)^2 for levels 0..5, then 524309 each).
    constexpr long long level_off[kLevels] = {
        0LL, 289LL, 1378LL, 5603LL, 22244LL, 88293LL, 351462LL,
        875771LL, 1400080LL, 1924389LL, 2448698LL, 2973007LL,
        3497316LL, 4021625LL, 4545934LL, 5070243LL
    };

    float acc[2 * kLevels];

#pragma unroll
    for (int l = 0; l < kLevels; ++l) {
        const int   scale_i = 16 << l;
        const float scale_f = (float)scale_i;

        const float fx = p.x * scale_f;
        const float fy = p.y * scale_f;

        // trunc-toward-zero int64 casts, additions done in fp32 (match jax)
        const long long ix0 = (long long)fx;
        const long long iy0 = (long long)fy;
        const long long ix1 = (long long)(fx + 1.0f);
        const long long iy1 = (long long)(fy + 1.0f);

        const float ox = fx - (float)ix0;
        const float oy = fy - (float)iy0;

        const float wx1 = fminf(fmaxf(ox, 0.0f), 1.0f);
        const float wx0 = fminf(fmaxf(1.0f - ox, 0.0f), 1.0f);
        const float wy1 = fminf(fmaxf(oy, 0.0f), 1.0f);
        const float wy0 = fminf(fmaxf(1.0f - oy, 0.0f), 1.0f);

        long long i00, i01, i10, i11;
        if (l < kStartHash) {
            const long long stride = (long long)(scale_i + 1);
            i00 = ix0 * stride + iy0;
            i01 = ix0 * stride + iy1;
            i10 = ix1 * stride + iy0;
            i11 = ix1 * stride + iy1;
        } else {
            const long long hy0 = iy0 * kPs1;
            const long long hy1 = iy1 * kPs1;
            i00 = (ix0 ^ hy0) % kEntries;
            i01 = (ix0 ^ hy1) % kEntries;
            i10 = (ix1 ^ hy0) % kEntries;
            i11 = (ix1 ^ hy1) % kEntries;
        }

        const long long base = level_off[l];
        const float2 v00 = tbl[base + i00];
        const float2 v01 = tbl[base + i01];
        const float2 v10 = tbl[base + i10];
        const float2 v11 = tbl[base + i11];

        const float w00 = wx0 * wy0;
        const float w01 = wx0 * wy1;
        const float w10 = wx1 * wy0;
        const float w11 = wx1 * wy1;

        acc[2 * l + 0] = w00 * v00.x + w01 * v01.x + w10 * v10.x + w11 * v11.x;
        acc[2 * l + 1] = w00 * v00.y + w01 * v01.y + w10 * v10.y + w11 * v11.y;
    }

    float4* o = out + (size_t)n * 8;
#pragma unroll
    for (int i = 0; i < 8; ++i) {
        o[i] = make_float4(acc[4 * i + 0], acc[4 * i + 1],
                           acc[4 * i + 2], acc[4 * i + 3]);
    }
}

extern "C" void kernel_launch(void* const* d_in, const int* in_sizes, int n_in,
                              void* d_out, int out_size, void* d_ws, size_t ws_size,
                              hipStream_t stream) {
    const float2* x   = (const float2*)d_in[0];
    const float2* tbl = (const float2*)d_in[1];
    float4*       out = (float4*)d_out;

    const int threads = 256;
    const int blocks  = kPoints / threads;  // 524288 / 256 = 2048
    hashgrid_fwd<<<blocks, threads, 0, stream>>>(x, tbl, out);
}

// Round 2
// 227.640 us; speedup vs baseline: 1.3517x; 1.3517x over previous
//
#include <hip/hip_runtime.h>

// Multires hash-grid encode (2D, instant-NGP style).
// Round 2: level-major two-pass structure.
//   Pass 1 (level_pass): thread = (level, point). Blocks ordered level-major so
//     the ~2048 resident blocks all work on ONE level at a time -> that level's
//     ~4.2 MB hash table fits each XCD's 4 MiB L2 -> gathers hit L2 instead of
//     fetching 64-B lines from memory (round-1 FETCH_SIZE was 730 MB vs ~50 MB
//     compulsory). Writes level-major ws[16][N] float2, fully coalesced.
//   Pass 2 (gather_out): transpose ws -> out[N,32]; both sides coalesce at
//     cache-line granularity.
// Index math replicates the jax reference bit-for-bit:
//   fx = x*scale (fp32); int corners = trunc_i64(fx + c) with the +1 in fp32;
//   frac = fx - (float)trunc_i64(fx);
//   levels 0..5 dense: idx = ix*(scale+1)+iy
//   levels 6..15 hash: idx = (ix ^ (iy*19349663)) % 524309
// Falls back to the single-pass round-1 kernel if ws_size < 64 MiB.

static constexpr int  kPoints    = 524288;
static constexpr int  kLevels    = 16;
static constexpr int  kStartHash = 6;
static constexpr long long kPs1     = 19349663LL;
static constexpr long long kEntries = 524309LL;

__constant__ long long c_level_off[kLevels] = {
    0LL, 289LL, 1378LL, 5603LL, 22244LL, 88293LL, 351462LL,
    875771LL, 1400080LL, 1924389LL, 2448698LL, 2973007LL,
    3497316LL, 4021625LL, 4545934LL, 5070243LL
};

__device__ __forceinline__ float2 interp_level(
    const float2 p, const float2* __restrict__ tbl, const int l)
{
    const int   scale_i = 16 << l;
    const float scale_f = (float)scale_i;

    const float fx = p.x * scale_f;
    const float fy = p.y * scale_f;

    const long long ix0 = (long long)fx;
    const long long iy0 = (long long)fy;
    const long long ix1 = (long long)(fx + 1.0f);
    const long long iy1 = (long long)(fy + 1.0f);

    const float ox = fx - (float)ix0;
    const float oy = fy - (float)iy0;

    const float wx1 = fminf(fmaxf(ox, 0.0f), 1.0f);
    const float wx0 = fminf(fmaxf(1.0f - ox, 0.0f), 1.0f);
    const float wy1 = fminf(fmaxf(oy, 0.0f), 1.0f);
    const float wy0 = fminf(fmaxf(1.0f - oy, 0.0f), 1.0f);

    long long i00, i01, i10, i11;
    if (l < kStartHash) {
        const long long stride = (long long)(scale_i + 1);
        i00 = ix0 * stride + iy0;
        i01 = ix0 * stride + iy1;
        i10 = ix1 * stride + iy0;
        i11 = ix1 * stride + iy1;
    } else {
        const long long hy0 = iy0 * kPs1;
        const long long hy1 = iy1 * kPs1;
        i00 = (ix0 ^ hy0) % kEntries;
        i01 = (ix0 ^ hy1) % kEntries;
        i10 = (ix1 ^ hy0) % kEntries;
        i11 = (ix1 ^ hy1) % kEntries;
    }

    const long long base = c_level_off[l];
    const float2 v00 = tbl[base + i00];
    const float2 v01 = tbl[base + i01];
    const float2 v10 = tbl[base + i10];
    const float2 v11 = tbl[base + i11];

    const float w00 = wx0 * wy0;
    const float w01 = wx0 * wy1;
    const float w10 = wx1 * wy0;
    const float w11 = wx1 * wy1;

    return make_float2(
        w00 * v00.x + w01 * v01.x + w10 * v10.x + w11 * v11.x,
        w00 * v00.y + w01 * v01.y + w10 * v10.y + w11 * v11.y);
}

// ---- Pass 1: level-major, one (level, point) per thread -------------------
__global__ __launch_bounds__(256) void level_pass(
    const float2* __restrict__ x,
    const float2* __restrict__ tbl,
    float2* __restrict__ ws)
{
    const int l = blockIdx.x >> 11;                         // 2048 blocks/level
    const int n = ((blockIdx.x & 2047) << 8) | threadIdx.x; // point id
    const float2 p = x[n];
    ws[(size_t)l * kPoints + n] = interp_level(p, tbl, l);
}

// ---- Pass 2: ws[16][N] float2 -> out[N][8] float4 -------------------------
__global__ __launch_bounds__(256) void gather_out(
    const float2* __restrict__ ws,
    float4* __restrict__ out)
{
    const int f = blockIdx.x * 256 + threadIdx.x;  // flat float4 index
    const int n = f >> 3;
    const int i = f & 7;
    const float2 a = ws[(size_t)(2 * i)     * kPoints + n];
    const float2 b = ws[(size_t)(2 * i + 1) * kPoints + n];
    out[f] = make_float4(a.x, a.y, b.x, b.y);
}

// ---- Fallback: round-1 single-pass kernel (if ws too small) ---------------
__global__ __launch_bounds__(256) void hashgrid_fwd(
    const float2* __restrict__ x,
    const float2* __restrict__ tbl,
    float4* __restrict__ out)
{
    const int n = blockIdx.x * blockDim.x + threadIdx.x;
    if (n >= kPoints) return;
    const float2 p = x[n];
    float acc[2 * kLevels];
#pragma unroll
    for (int l = 0; l < kLevels; ++l) {
        const float2 r = interp_level(p, tbl, l);
        acc[2 * l + 0] = r.x;
        acc[2 * l + 1] = r.y;
    }
    float4* o = out + (size_t)n * 8;
#pragma unroll
    for (int i = 0; i < 8; ++i)
        o[i] = make_float4(acc[4 * i + 0], acc[4 * i + 1],
                           acc[4 * i + 2], acc[4 * i + 3]);
}

extern "C" void kernel_launch(void* const* d_in, const int* in_sizes, int n_in,
                              void* d_out, int out_size, void* d_ws, size_t ws_size,
                              hipStream_t stream) {
    const float2* x   = (const float2*)d_in[0];
    const float2* tbl = (const float2*)d_in[1];

    const size_t ws_needed = (size_t)kLevels * kPoints * sizeof(float2); // 64 MiB
    if (ws_size >= ws_needed) {
        float2* ws = (float2*)d_ws;
        level_pass<<<kLevels * (kPoints / 256), 256, 0, stream>>>(x, tbl, ws);
        gather_out<<<(kPoints * 8) / 256, 256, 0, stream>>>(ws, (float4*)d_out);
    } else {
        hashgrid_fwd<<<kPoints / 256, 256, 0, stream>>>(x, tbl, (float4*)d_out);
    }
}

// Round 3
// 226.951 us; speedup vs baseline: 1.3558x; 1.0030x over previous
//
#include <hip/hip_runtime.h>

// Multires hash-grid encode (2D, instant-NGP style). Round 3.
// Pass 1 (level_pass): XCD-partitioned level-major gather.
//   blockIdx % 8 empirically round-robins over the 8 XCDs, so we assign:
//     slots    0..2047 : hashed level 6+xcd  (each XCD owns ONE ~4.19 MB table
//                        -> random gathers become L2 hits, no 8x XCD dup)
//     slots 2048..2303 : level 14, split 8 ways by xcd
//     slots 2304..2559 : level 15, split 8 ways by xcd
//     slots 2560..4095 : dense levels 0..5 (tables sum 2.8 MB, L2-trivial)
//   Writes level-major ws[16][N] float2, coalesced. Mapping is a perf
//   heuristic only — any XCD assignment is still correct.
// Pass 2 (transpose_out): LDS-tiled transpose ws[16][N] -> out[N][32].
//   Reads 2-KB contiguous per level, writes coalesced float4. LDS stride 257
//   float2 breaks the 512-dword (mod-32-bank) conflict pattern.
// Index math replicates the jax reference bit-for-bit (see interp_level).

static constexpr int  kPoints    = 524288;
static constexpr int  kLevels    = 16;
static constexpr int  kStartHash = 6;
static constexpr long long kPs1     = 19349663LL;
static constexpr long long kEntries = 524309LL;

__constant__ long long c_level_off[kLevels] = {
    0LL, 289LL, 1378LL, 5603LL, 22244LL, 88293LL, 351462LL,
    875771LL, 1400080LL, 1924389LL, 2448698LL, 2973007LL,
    3497316LL, 4021625LL, 4545934LL, 5070243LL
};

__device__ __forceinline__ float2 interp_level(
    const float2 p, const float2* __restrict__ tbl, const int l)
{
    const int   scale_i = 16 << l;
    const float scale_f = (float)scale_i;

    const float fx = p.x * scale_f;
    const float fy = p.y * scale_f;

    const long long ix0 = (long long)fx;
    const long long iy0 = (long long)fy;
    const long long ix1 = (long long)(fx + 1.0f);
    const long long iy1 = (long long)(fy + 1.0f);

    const float ox = fx - (float)ix0;
    const float oy = fy - (float)iy0;

    const float wx1 = fminf(fmaxf(ox, 0.0f), 1.0f);
    const float wx0 = fminf(fmaxf(1.0f - ox, 0.0f), 1.0f);
    const float wy1 = fminf(fmaxf(oy, 0.0f), 1.0f);
    const float wy0 = fminf(fmaxf(1.0f - oy, 0.0f), 1.0f);

    long long i00, i01, i10, i11;
    if (l < kStartHash) {
        const long long stride = (long long)(scale_i + 1);
        i00 = ix0 * stride + iy0;
        i01 = ix0 * stride + iy1;
        i10 = ix1 * stride + iy0;
        i11 = ix1 * stride + iy1;
    } else {
        const long long hy0 = iy0 * kPs1;
        const long long hy1 = iy1 * kPs1;
        i00 = (ix0 ^ hy0) % kEntries;
        i01 = (ix0 ^ hy1) % kEntries;
        i10 = (ix1 ^ hy0) % kEntries;
        i11 = (ix1 ^ hy1) % kEntries;
    }

    const long long base = c_level_off[l];
    const float2 v00 = tbl[base + i00];
    const float2 v01 = tbl[base + i01];
    const float2 v10 = tbl[base + i10];
    const float2 v11 = tbl[base + i11];

    const float w00 = wx0 * wy0;
    const float w01 = wx0 * wy1;
    const float w10 = wx1 * wy0;
    const float w11 = wx1 * wy1;

    return make_float2(
        w00 * v00.x + w01 * v01.x + w10 * v10.x + w11 * v11.x,
        w00 * v00.y + w01 * v01.y + w10 * v10.y + w11 * v11.y);
}

// ---- Pass 1: XCD-partitioned level-major --------------------------------
__global__ __launch_bounds__(256) void level_pass(
    const float2* __restrict__ x,
    const float2* __restrict__ tbl,
    float2* __restrict__ ws)
{
    const int b    = blockIdx.x;
    const int xcd  = b & 7;
    const int slot = b >> 3;        // 0..4095, roughly synchronized across XCDs

    int level, pblk;
    if (slot < 2048) {
        level = 6 + xcd;            // hashed levels 6..13, one per XCD
        pblk  = slot;
    } else if (slot < 2304) {
        level = 14;                 // split 8 ways
        pblk  = xcd * 256 + (slot - 2048);
    } else if (slot < 2560) {
        level = 15;                 // split 8 ways
        pblk  = xcd * 256 + (slot - 2304);
    } else {
        const int d = xcd * 1536 + (slot - 2560);  // 0..12287
        level = d >> 11;            // dense levels 0..5
        pblk  = d & 2047;
    }

    const int n = (pblk << 8) | threadIdx.x;
    const float2 p = x[n];
    ws[(size_t)level * kPoints + n] = interp_level(p, tbl, level);
}

// ---- Pass 2: LDS-tiled transpose ws[16][N] -> out[N][8] float4 ----------
static constexpr int kTStride = 257;  // float2 elems per level row in LDS

__global__ __launch_bounds__(256) void transpose_out(
    const float2* __restrict__ ws,
    float4* __restrict__ out)
{
    __shared__ float2 lds[kLevels * kTStride];  // ~32.9 KB

    const int t  = threadIdx.x;
    const int n0 = blockIdx.x * 256;

#pragma unroll
    for (int l = 0; l < kLevels; ++l)
        lds[l * kTStride + t] = ws[(size_t)l * kPoints + n0 + t];

    __syncthreads();

    float4* o = out + (size_t)n0 * 8;
#pragma unroll
    for (int k = 0; k < 8; ++k) {
        const int f  = k * 256 + t;
        const int nl = f >> 3;
        const int i  = t & 7;
        const float2 a = lds[(2 * i)     * kTStride + nl];
        const float2 b = lds[(2 * i + 1) * kTStride + nl];
        o[f] = make_float4(a.x, a.y, b.x, b.y);
    }
}

// ---- Fallback: single-pass (if ws too small) ----------------------------
__global__ __launch_bounds__(256) void hashgrid_fwd(
    const float2* __restrict__ x,
    const float2* __restrict__ tbl,
    float4* __restrict__ out)
{
    const int n = blockIdx.x * blockDim.x + threadIdx.x;
    if (n >= kPoints) return;
    const float2 p = x[n];
    float acc[2 * kLevels];
#pragma unroll
    for (int l = 0; l < kLevels; ++l) {
        const float2 r = interp_level(p, tbl, l);
        acc[2 * l + 0] = r.x;
        acc[2 * l + 1] = r.y;
    }
    float4* o = out + (size_t)n * 8;
#pragma unroll
    for (int i = 0; i < 8; ++i)
        o[i] = make_float4(acc[4 * i + 0], acc[4 * i + 1],
                           acc[4 * i + 2], acc[4 * i + 3]);
}

extern "C" void kernel_launch(void* const* d_in, const int* in_sizes, int n_in,
                              void* d_out, int out_size, void* d_ws, size_t ws_size,
                              hipStream_t stream) {
    const float2* x   = (const float2*)d_in[0];
    const float2* tbl = (const float2*)d_in[1];

    const size_t ws_needed = (size_t)kLevels * kPoints * sizeof(float2); // 64 MiB
    if (ws_size >= ws_needed) {
        float2* ws = (float2*)d_ws;
        level_pass<<<kLevels * (kPoints / 256), 256, 0, stream>>>(x, tbl, ws);
        transpose_out<<<kPoints / 256, 256, 0, stream>>>(ws, (float4*)d_out);
    } else {
        hashgrid_fwd<<<kPoints / 256, 256, 0, stream>>>(x, tbl, (float4*)d_out);
    }
}